// Round 5
// baseline (119.530 us; speedup 1.0000x reference)
//
#include <hip/hip_runtime.h>

#define COLS 117
#define NOUT1 20
#define ROWS 64                  // rows per tile/block
#define THREADS 512              // 8 waves
#define NV (ROWS * COLS / 4)     // 1872 float4 per tile
#define FULLS (NV / THREADS)     // 3 full sweeps
#define REMV (NV - FULLS * THREADS)  // 336 leftover float4
#define PSTR 21                  // padded partial stride (odd -> conflict-free)
#define PFROW (ROWS * PSTR)      // 1344 floats per partial region

// requant: y = x*m (fp32 round), y += off (fp32 round), trunc toward zero to
// int64, arithmetic >> s, clamp [0,255]. Matches jnp reference exactly.
__device__ __forceinline__ float requant(float x, float m, float off, int s) {
  float y = __fmul_rn(x, m);
  y = __fadd_rn(y, off);
  long long yi = (long long)y;   // trunc toward zero, like astype(int64)
  yi >>= s;                      // arithmetic shift
  float r = (float)yi;
  return fminf(fmaxf(r, 0.0f), 255.0f);
}

// Transpose W1 [20,117] -> W1T [117,20]: weights for a given k contiguous.
__global__ void transpose_w1(const float* __restrict__ W1, float* __restrict__ w1t) {
  for (int idx = threadIdx.x; idx < NOUT1 * COLS; idx += blockDim.x) {
    int o = idx / COLS, k = idx % COLS;
    w1t[k * NOUT1 + o] = W1[idx];
  }
}

// 512-thread / 8-wave blocks, 64-row tile, 4 blocks/CU = 32 waves/CU (max).
// R1-R4 law: BW duty ~ linear in waves/CU (8w->31%, 20w->70%); this targets
// the 32-wave ceiling while keeping the proven R2 recipe: coalesced float4
// staging, 1 lane = 1 row, wave-uniform column slices -> scalar weight loads.
// Wave w covers kn in {15 (w<5), 14 (w>=5)} columns. 8-wave reduce is a
// two-stage merge in the reused x buffer (regions are exclusive, no races).
template <bool TW>
__global__ __launch_bounds__(THREADS, 8) void fann_kernel(
    const float* __restrict__ X, const float* __restrict__ W1,
    const float* __restrict__ b1, const float* __restrict__ W2,
    const float* __restrict__ b2, float* __restrict__ out) {
  __shared__ __align__(16) float xs[ROWS * COLS];  // 29,952 B
  float4* xs4 = (float4*)xs;
  const int tid = threadIdx.x;
  {
    const float4* __restrict__ src =
        reinterpret_cast<const float4*>(X) + (size_t)blockIdx.x * NV;
    #pragma unroll
    for (int i = 0; i < FULLS; ++i) xs4[tid + i * THREADS] = src[tid + i * THREADS];
    if (tid < REMV) xs4[tid + FULLS * THREADS] = src[tid + FULLS * THREADS];
  }
  __syncthreads();  // #0: tile staged

  const int w = __builtin_amdgcn_readfirstlane(tid >> 6);  // wave id in SGPR
  const int l = tid & 63;                                  // row (1 lane/row)
  const int k0 = (w < 5) ? 15 * w : 75 + 14 * (w - 5);
  const int kn = (w < 5) ? 15 : 14;   // wave-uniform trip count

  float acc[NOUT1];
  #pragma unroll
  for (int o = 0; o < NOUT1; ++o) acc[o] = 0.0f;
  const float* xr = xs + l * COLS + k0;  // lane stride 117 (odd) -> free

  if (TW) {
    const float4* __restrict__ w4 =
        reinterpret_cast<const float4*>(W1) + (size_t)k0 * (NOUT1 / 4);
    for (int kk = 0; kk < kn; ++kk) {
      float x = xr[kk];
      #pragma unroll
      for (int j = 0; j < 5; ++j) {
        float4 wv = w4[kk * 5 + j];   // uniform address -> s_load
        acc[4 * j + 0] = fmaf(x, wv.x, acc[4 * j + 0]);
        acc[4 * j + 1] = fmaf(x, wv.y, acc[4 * j + 1]);
        acc[4 * j + 2] = fmaf(x, wv.z, acc[4 * j + 2]);
        acc[4 * j + 3] = fmaf(x, wv.w, acc[4 * j + 3]);
      }
    }
  } else {
    for (int kk = 0; kk < kn; ++kk) {
      float x = xr[kk];
      #pragma unroll
      for (int o = 0; o < NOUT1; ++o)
        acc[o] = fmaf(x, W1[o * COLS + k0 + kk], acc[o]);
    }
  }
  __syncthreads();  // #1: all x reads of xs done -> safe to overwrite

  // Two-stage 8-wave merge into A[4][64][21] (reusing xs):
  if (w < 4) {      // stage A: waves 0-3 write their partials
    float* pw = xs + w * PFROW + l * PSTR;
    #pragma unroll
    for (int o = 0; o < NOUT1; ++o) pw[o] = acc[o];
  }
  __syncthreads();  // #2: A written
  if (w >= 4) {     // stage B: waves 4-7 add into region (w-4), exclusive owner
    float* pw = xs + (w - 4) * PFROW + l * PSTR;
    #pragma unroll
    for (int o = 0; o < NOUT1; ++o) pw[o] += acc[o];
  }
  __syncthreads();  // #3: merge done

  // Parallel stage-2 (R2 pattern): wave w<4 reduces outputs 5w..5w+4 for all
  // rows, requants, accumulates layer-2 partials into sp0/sp1.
  float* sp0 = xs + 4 * PFROW;   // [4][65]  (5376..5896)
  float* sp1 = sp0 + 4 * 65;     // (5896..6416) < 7488 ✓
  if (w < 4) {
    float s0 = 0.0f, s1 = 0.0f;
    #pragma unroll
    for (int j = 0; j < 5; ++j) {
      const int o = w * 5 + j;
      float h = xs[0 * PFROW + l * PSTR + o] + xs[1 * PFROW + l * PSTR + o] +
                xs[2 * PFROW + l * PSTR + o] + xs[3 * PFROW + l * PSTR + o];
      h += b1[o];
      float hq = requant(h, 1565.0f, 16384.0f, 15);
      s0 = fmaf(hq, W2[o], s0);
      s1 = fmaf(hq, W2[NOUT1 + o], s1);
    }
    sp0[w * 65 + l] = s0;
    sp1[w * 65 + l] = s1;
  }
  __syncthreads();  // #4: layer-2 partials visible

  if (tid < ROWS) {
    float s0 = sp0[tid] + sp0[65 + tid] + sp0[130 + tid] + sp0[195 + tid] + b2[0];
    float s1 = sp1[tid] + sp1[65 + tid] + sp1[130 + tid] + sp1[195 + tid] + b2[1];
    float2 r;
    r.x = requant(s0, 1342.0f, 16384.0f, 15);
    r.y = requant(s1, 1342.0f, 16384.0f, 15);
    reinterpret_cast<float2*>(out)[(size_t)blockIdx.x * ROWS + tid] = r;
  }
}

// Tail for row counts not divisible by ROWS (not hit for B=1048576).
__global__ void fann_tail(const float* __restrict__ X, const float* __restrict__ W1,
                          const float* __restrict__ b1, const float* __restrict__ W2,
                          const float* __restrict__ b2, float* __restrict__ out,
                          int start, int B) {
  int row = start + blockIdx.x * blockDim.x + threadIdx.x;
  if (row >= B) return;
  float acc[NOUT1];
  #pragma unroll
  for (int o = 0; o < NOUT1; ++o) acc[o] = b1[o];
  const float* xr = X + (size_t)row * COLS;
  for (int k = 0; k < COLS; ++k) {
    float x = xr[k];
    #pragma unroll
    for (int o = 0; o < NOUT1; ++o) acc[o] = fmaf(x, W1[o * COLS + k], acc[o]);
  }
  float s0 = b2[0], s1 = b2[1];
  #pragma unroll
  for (int o = 0; o < NOUT1; ++o) {
    float hq = requant(acc[o], 1565.0f, 16384.0f, 15);
    s0 = fmaf(hq, W2[o], s0);
    s1 = fmaf(hq, W2[NOUT1 + o], s1);
  }
  out[(size_t)row * 2 + 0] = requant(s0, 1342.0f, 16384.0f, 15);
  out[(size_t)row * 2 + 1] = requant(s1, 1342.0f, 16384.0f, 15);
}

extern "C" void kernel_launch(void* const* d_in, const int* in_sizes, int n_in,
                              void* d_out, int out_size, void* d_ws, size_t ws_size,
                              hipStream_t stream) {
  const float* X  = (const float*)d_in[0];
  const float* W1 = (const float*)d_in[1];
  const float* b1 = (const float*)d_in[2];
  const float* W2 = (const float*)d_in[3];
  const float* b2 = (const float*)d_in[4];
  float* out = (float*)d_out;
  const int B = in_sizes[0] / COLS;
  const int nblk = B / ROWS;
  const int tail = B - nblk * ROWS;

  const bool useT = ws_size >= (size_t)(COLS * NOUT1 * sizeof(float));
  if (useT) {
    float* w1t = (float*)d_ws;
    transpose_w1<<<1, 256, 0, stream>>>(W1, w1t);
    if (nblk > 0)
      fann_kernel<true><<<nblk, THREADS, 0, stream>>>(X, w1t, b1, W2, b2, out);
  } else {
    if (nblk > 0)
      fann_kernel<false><<<nblk, THREADS, 0, stream>>>(X, W1, b1, W2, b2, out);
  }
  if (tail > 0)
    fann_tail<<<(tail + 63) / 64, 64, 0, stream>>>(X, W1, b1, W2, b2, out,
                                                   nblk * ROWS, B);
}

// Round 8
// 110.746 us; speedup vs baseline: 1.0793x; 1.0793x over previous
//
#include <hip/hip_runtime.h>

#define COLS 117
#define NOUT1 20
#define ROWS 64                // rows per block (= wave width, 1 lane/row)
#define NV (ROWS * COLS / 4)   // 1872 float4 per tile
#define REM (NV - 7 * 256)     // 80 leftover float4 after 7 full sweeps
#define PSTR 21                // padded partial stride (odd -> conflict-free)
#define PFROW (ROWS * PSTR)    // 1344

// requant: y = x*m (fp32 round), y += off (fp32 round), trunc toward zero to
// int64, arithmetic >> s, clamp [0,255]. Matches jnp reference exactly.
__device__ __forceinline__ float requant(float x, float m, float off, int s) {
  float y = __fmul_rn(x, m);
  y = __fadd_rn(y, off);
  long long yi = (long long)y;   // trunc toward zero, like astype(int64)
  yi >>= s;                      // arithmetic shift
  float r = (float)yi;
  return fminf(fmaxf(r, 0.0f), 255.0f);
}

// Transpose W1 [20,117] -> W1T [117,20]: weights for a given k contiguous.
__global__ void transpose_w1(const float* __restrict__ W1, float* __restrict__ w1t) {
  for (int idx = threadIdx.x; idx < NOUT1 * COLS; idx += blockDim.x) {
    int o = idx / COLS, k = idx % COLS;
    w1t[k * NOUT1 + o] = W1[idx];
  }
}

// R2 geometry (empirical optimum: 20 waves/CU, 5 blocks x 4 waves), minus two
// overheads: (1) staging via global_load_lds width=16 (no VGPR round-trip,
// LDS dest linear = lane-order rule, m104); (2) fused tail: partial reduce +
// requant + layer-2 done by all 4 waves with a 3-shfl serial gather that
// preserves R2's exact (((g0+g1)+g2)+g3)+b2 order; kills barrier #3 and the
// sp0/sp1 round-trip. Barriers: #0 post-stage, #1 post-kloop, #2 partials.
template <bool TW>
__global__ __launch_bounds__(256, 5) void fann_kernel(
    const float* __restrict__ X, const float* __restrict__ W1,
    const float* __restrict__ b1, const float* __restrict__ W2,
    const float* __restrict__ b2, float* __restrict__ out) {
  __shared__ __align__(16) float xs[ROWS * COLS];  // 29,952 B -> 5 blocks/CU
  float4* xs4 = (float4*)xs;
  const int t = threadIdx.x;
  {
    const float4* __restrict__ src =
        reinterpret_cast<const float4*>(X) + (size_t)blockIdx.x * NV;
    // Direct global->LDS DMA; dest is wave-uniform base + lane*16 (linear,
    // matches xs4[t + i*256] exactly). Tail is exec-masked (lanes 0-15 of
    // wave 1 + wave 0): physical lane id drives the LDS offset, so masked
    // lanes simply don't transfer.
    #pragma unroll
    for (int i = 0; i < 7; ++i)
      __builtin_amdgcn_global_load_lds(
          (const __attribute__((address_space(1))) void*)&src[t + i * 256],
          (__attribute__((address_space(3))) void*)&xs4[t + i * 256], 16, 0, 0);
    if (t < REM)
      __builtin_amdgcn_global_load_lds(
          (const __attribute__((address_space(1))) void*)&src[t + 7 * 256],
          (__attribute__((address_space(3))) void*)&xs4[t + 7 * 256], 16, 0, 0);
  }
  __syncthreads();  // #0: tile staged (drains vmcnt)

  const int w = __builtin_amdgcn_readfirstlane(t >> 6);  // wave id in SGPR
  const int l = t & 63;                                  // row within tile
  const int k0 = w * 29;
  const int kn = (w == 3) ? 30 : 29;   // wave-uniform trip count

  float acc[NOUT1];
  #pragma unroll
  for (int o = 0; o < NOUT1; ++o) acc[o] = 0.0f;
  const float* xr = xs + l * COLS + k0;  // lane stride 117 (odd) -> free

  if (TW) {
    const float4* __restrict__ w4 =
        reinterpret_cast<const float4*>(W1) + (size_t)k0 * (NOUT1 / 4);
    for (int kk = 0; kk < kn; ++kk) {
      float x = xr[kk];
      #pragma unroll
      for (int j = 0; j < 5; ++j) {
        float4 wv = w4[kk * 5 + j];   // uniform address -> s_load
        acc[4 * j + 0] = fmaf(x, wv.x, acc[4 * j + 0]);
        acc[4 * j + 1] = fmaf(x, wv.y, acc[4 * j + 1]);
        acc[4 * j + 2] = fmaf(x, wv.z, acc[4 * j + 2]);
        acc[4 * j + 3] = fmaf(x, wv.w, acc[4 * j + 3]);
      }
    }
  } else {
    for (int kk = 0; kk < kn; ++kk) {
      float x = xr[kk];
      #pragma unroll
      for (int o = 0; o < NOUT1; ++o)
        acc[o] = fmaf(x, W1[o * COLS + k0 + kk], acc[o]);
    }
  }
  __syncthreads();  // #1: all x reads of xs done -> safe to overwrite

  {  // partials A[w][row][o], stride 21 (odd) -> conflict-free
    float* pw = xs + w * PFROW + l * PSTR;
    #pragma unroll
    for (int o = 0; o < NOUT1; ++o) pw[o] = acc[o];
  }
  __syncthreads();  // #2: partials visible

  // Fused tail, all 256 lanes busy. Wave w owns rows 16w..16w+15; within the
  // wave, lane l: row r = 16w + (l&15), output-group og = l>>4 covers outputs
  // 5og..5og+4. Exact R2 arithmetic orders:
  //   h   = ((A0 + A1) + A2) + A3, then += b1[o]
  //   g   = sequential fmaf over the group's 5 outputs from 0
  //   s   = (((g0 + g1) + g2) + g3) + b2   (serial shfl gather to og0 lanes)
  {
    const int r  = (w << 4) + (l & 15);
    const int og = l >> 4;
    float g0 = 0.0f, g1 = 0.0f;
    #pragma unroll
    for (int j = 0; j < 5; ++j) {
      const int o = og * 5 + j;
      const float* pa = xs + r * PSTR + o;
      float h = pa[0 * PFROW] + pa[1 * PFROW] + pa[2 * PFROW] + pa[3 * PFROW];
      h += b1[o];
      float hq = requant(h, 1565.0f, 16384.0f, 15);
      g0 = fmaf(hq, W2[o], g0);
      g1 = fmaf(hq, W2[NOUT1 + o], g1);
    }
    const int lb = l & 15;
    float a01 = __shfl(g0, lb + 16);
    float a02 = __shfl(g0, lb + 32);
    float a03 = __shfl(g0, lb + 48);
    float a11 = __shfl(g1, lb + 16);
    float a12 = __shfl(g1, lb + 32);
    float a13 = __shfl(g1, lb + 48);
    if (og == 0) {
      float s0 = ((g0 + a01) + a02) + a03 + b2[0];
      float s1 = ((g1 + a11) + a12) + a13 + b2[1];
      float2 res;
      res.x = requant(s0, 1342.0f, 16384.0f, 15);
      res.y = requant(s1, 1342.0f, 16384.0f, 15);
      reinterpret_cast<float2*>(out)[(size_t)blockIdx.x * ROWS + r] = res;
    }
  }
}

// Tail for row counts not divisible by ROWS (not hit for B=1048576).
__global__ void fann_tail(const float* __restrict__ X, const float* __restrict__ W1,
                          const float* __restrict__ b1, const float* __restrict__ W2,
                          const float* __restrict__ b2, float* __restrict__ out,
                          int start, int B) {
  int row = start + blockIdx.x * blockDim.x + threadIdx.x;
  if (row >= B) return;
  float acc[NOUT1];
  #pragma unroll
  for (int o = 0; o < NOUT1; ++o) acc[o] = b1[o];
  const float* xr = X + (size_t)row * COLS;
  for (int k = 0; k < COLS; ++k) {
    float x = xr[k];
    #pragma unroll
    for (int o = 0; o < NOUT1; ++o) acc[o] = fmaf(x, W1[o * COLS + k], acc[o]);
  }
  float s0 = b2[0], s1 = b2[1];
  #pragma unroll
  for (int o = 0; o < NOUT1; ++o) {
    float hq = requant(acc[o], 1565.0f, 16384.0f, 15);
    s0 = fmaf(hq, W2[o], s0);
    s1 = fmaf(hq, W2[NOUT1 + o], s1);
  }
  out[(size_t)row * 2 + 0] = requant(s0, 1342.0f, 16384.0f, 15);
  out[(size_t)row * 2 + 1] = requant(s1, 1342.0f, 16384.0f, 15);
}

extern "C" void kernel_launch(void* const* d_in, const int* in_sizes, int n_in,
                              void* d_out, int out_size, void* d_ws, size_t ws_size,
                              hipStream_t stream) {
  const float* X  = (const float*)d_in[0];
  const float* W1 = (const float*)d_in[1];
  const float* b1 = (const float*)d_in[2];
  const float* W2 = (const float*)d_in[3];
  const float* b2 = (const float*)d_in[4];
  float* out = (float*)d_out;
  const int B = in_sizes[0] / COLS;
  const int nblk = B / ROWS;
  const int tail = B - nblk * ROWS;

  const bool useT = ws_size >= (size_t)(COLS * NOUT1 * sizeof(float));
  if (useT) {
    float* w1t = (float*)d_ws;
    transpose_w1<<<1, 256, 0, stream>>>(W1, w1t);
    if (nblk > 0)
      fann_kernel<true><<<nblk, 256, 0, stream>>>(X, w1t, b1, W2, b2, out);
  } else {
    if (nblk > 0)
      fann_kernel<false><<<nblk, 256, 0, stream>>>(X, W1, b1, W2, b2, out);
  }
  if (tail > 0)
    fann_tail<<<(tail + 63) / 64, 64, 0, stream>>>(X, W1, b1, W2, b2, out,
                                                   nblk * ROWS, B);
}